// Round 2
// baseline (448.602 us; speedup 1.0000x reference)
//
#include <hip/hip_runtime.h>
#include <hip/hip_bf16.h>

// Dtypes: ALL inputs and the output are float32 (per reference; the 0.56
// threshold is exactly 2% of max|ref|=28 -> plain f32 rule, and round-1's
// NaN matched the inf-inf signature of misreading f32 bits as bf16).
// GEMM precision: split-bf16 on BOTH operands, xy = AhBh + (AhBl + AlBh),
// f32-grade accuracy at 3x MFMA cost (needed: artanh amplifies xy err ~1000x).

typedef __attribute__((ext_vector_type(8))) short short8;
typedef __attribute__((ext_vector_type(4))) float f32x4;
typedef unsigned short u16;

__device__ inline float bits2f(unsigned u){ union{unsigned u; float f;} x; x.u=u; return x.f; }
__device__ inline u16 f2bf(float f){
  union { float f; unsigned u; } x; x.f = f;
  unsigned r = x.u + 0x7fff + ((x.u >> 16) & 1);   // round-to-nearest-even
  return (u16)(r >> 16);
}
__device__ inline void bfsplit(float f, u16 &h, u16 &l){
  u16 hb = f2bf(f);
  float hf = bits2f(((unsigned)hb) << 16);
  h = hb;
  l = f2bf(f - hf);
}

__device__ inline float wred(float x){
#pragma unroll
  for (int off = 32; off; off >>= 1) x += __shfl_xor(x, off, 64);
  return x;
}

__device__ inline float dotW(const float* __restrict__ w, const float* __restrict__ p){
  float m = 0.f;
#pragma unroll
  for (int i = 0; i < 32; ++i){
    float4 u = *(const float4*)(w + 4*i);
    const float* q = p + 4*i;
    m = fmaf(u.x, q[0], m); m = fmaf(u.y, q[1], m);
    m = fmaf(u.z, q[2], m); m = fmaf(u.w, q[3], m);
  }
  return m;
}

// ---------------- Kernel 1: per-row hyperbolic MLP chain (f32) ----------------
// 1 wave per row; each lane owns elements 2*lane, 2*lane+1.
__global__ __launch_bounds__(64) void prep_kernel(
    const float* __restrict__ vt, const float* __restrict__ Wm,
    const float* __restrict__ bias,
    u16* __restrict__ ahi, u16* __restrict__ alo, float* __restrict__ x2o)
{
  const int row = blockIdx.x, lane = threadIdx.x;
  const int e0 = 2*lane;
  const float CLIP = 0.99999f;  // 1 - 1e-5

  float v0 = vt[row*128 + e0];
  float v1 = vt[row*128 + e0 + 1];
  // p1 = expmap0(v)
  float n1 = fmaxf(sqrtf(wred(v0*v0 + v1*v1)), 1e-15f);
  float s1 = tanhf(n1)/n1;
  float p0 = s1*v0, p1 = s1*v1;
  __shared__ float sP[128];
  sP[e0] = p0; sP[e0+1] = p1;
  __syncthreads();
  float xn = fmaxf(sqrtf(wred(p0*p0 + p1*p1)), 1e-15f);
  // Mx = p1 @ W.T  (Mx[i] = sum_j p1[j]*W[i][j])
  float mx0 = dotW(Wm + e0*128, sP);
  float mx1 = dotW(Wm + (e0+1)*128, sP);
  float Mxn = fmaxf(sqrtf(wred(mx0*mx0 + mx1*mx1)), 1e-15f);
  float smv = tanhf((Mxn/xn) * atanhf(fminf(xn, CLIP))) / Mxn;
  float m0 = smv*mx0, m1 = smv*mx1;
  // eb = expmap0(b)
  float b0 = bias[e0], b1 = bias[e0+1];
  float nb = fmaxf(sqrtf(wred(b0*b0 + b1*b1)), 1e-15f);
  float sb = tanhf(nb)/nb;
  float eb0 = sb*b0, eb1 = sb*b1;
  // mobius_add(m, eb)
  float x2m = wred(m0*m0 + m1*m1);
  float y2e = wred(eb0*eb0 + eb1*eb1);
  float xy  = wred(m0*eb0 + m1*eb1);
  float ca = 1.f + 2.f*xy + y2e;
  float cb = 1.f - x2m;
  float den = fmaxf(1.f + 2.f*xy + x2m*y2e, 1e-15f);
  float q0 = (ca*m0 + cb*eb0)/den, q1 = (ca*m1 + cb*eb1)/den;
  // logmap0 then expmap0
  float n2 = fmaxf(sqrtf(wred(q0*q0 + q1*q1)), 1e-15f);
  float u = atanhf(fminf(n2, CLIP));
  float sv = u/n2;
  float w0v = sv*q0, w1v = sv*q1;
  float n3 = fmaxf(sqrtf(wred(w0v*w0v + w1v*w1v)), 1e-15f);
  float s3 = tanhf(n3)/n3;
  float P0 = s3*w0v, P1 = s3*w1v;
  float x2v = wred(P0*P0 + P1*P1);
  // split-bf16: hi + lo
  u16 h0, l0, h1, l1;
  bfsplit(P0, h0, l0); bfsplit(P1, h1, l1);
  ahi[row*128 + e0] = h0; ahi[row*128 + e0 + 1] = h1;
  alo[row*128 + e0] = l0; alo[row*128 + e0 + 1] = l1;
  if (lane == 0) x2o[row] = x2v;
}

// ---------------- Kernel 2: y2[k] = ||code_k||^2 (f32) ----------------
__global__ __launch_bounds__(256) void y2_kernel(
    const float* __restrict__ code, float* __restrict__ y2o)
{
  int k = blockIdx.x*256 + threadIdx.x;
  const float* r = code + (size_t)k*128;
  float s = 0.f;
#pragma unroll
  for (int i = 0; i < 32; ++i){
    float4 u = *(const float4*)(r + 4*i);
    s = fmaf(u.x,u.x,s); s = fmaf(u.y,u.y,s);
    s = fmaf(u.z,u.z,s); s = fmaf(u.w,u.w,s);
  }
  y2o[k] = s;
}

// ---------------- Kernel 3: split-bf16 GEMM + fused hyperbolic-dist epilogue ----
// Block: 256 thr = 4 waves, 64 rows (16/wave, A persistent in regs), 256 cols.
// Grid: (125 col-chunks, 32 row-groups). B tiles (64 cols x K=128) split to
// bf16 hi/lo in LDS at staging time. xy = AhBh + (AhBl + AlBh).
#define SBS 136   // 128 + 8 u16 pad; 272B row stride keeps 16B alignment

__global__ __launch_bounds__(256, 4) void decode_main(
    const float* __restrict__ code, const u16* __restrict__ ahi_g,
    const u16* __restrict__ alo_g, const float* __restrict__ x2g,
    const float* __restrict__ y2g, const float* __restrict__ fbg,
    const float* __restrict__ tempg, float* __restrict__ outp)
{
  __shared__ u16 sBh[64*SBS];
  __shared__ u16 sBl[64*SBS];
  const int tid  = threadIdx.x;
  const int wave = tid >> 6, lane = tid & 63;
  const int quad = lane >> 4, l16 = lane & 15;
  const int m0 = blockIdx.y*64 + wave*16;
  const int arow = m0 + l16;

  // Persistent A fragments: 16 rows x K=128, hi+lo (A[m=lane&15][k=quad*8+j])
  short8 ah[4], al[4];
#pragma unroll
  for (int ks = 0; ks < 4; ++ks){
    ah[ks] = *(const short8*)(ahi_g + arow*128 + ks*32 + quad*8);
    al[ks] = *(const short8*)(alo_g + arow*128 + ks*32 + quad*8);
  }
  // Per-accumulator-row precomputes (C row = quad*4 + r)
  float x2v[4], ntb[4], b2[4];
#pragma unroll
  for (int r = 0; r < 4; ++r){
    float xv = x2g[m0 + quad*4 + r];
    x2v[r] = xv;
    float bb = 1.f - xv;
    ntb[r] = -2.f*bb;
    b2[r]  = bb*bb;
  }
  const float tmp  = tempg[0];
  const float nit2 = -1.f/(tmp*tmp);   // out = fb - d^2/t^2
  const int n_base = blockIdx.x*256;

  for (int rnd = 0; rnd < 4; ++rnd){
    const int n0r = n_base + rnd*64;
    __syncthreads();
    // stage 64 cols x K=128 f32 of B, splitting to bf16 hi/lo in LDS
#pragma unroll
    for (int i = 0; i < 8; ++i){
      int id = tid + i*256;            // 0..2047 float4-chunks
      int c = id >> 5, sg = id & 31;   // col, float4 index within row
      float4 u = *(const float4*)(code + (size_t)(n0r + c)*128 + sg*4);
      u16 h0,h1,h2,h3,l0,l1,l2,l3;
      bfsplit(u.x,h0,l0); bfsplit(u.y,h1,l1);
      bfsplit(u.z,h2,l2); bfsplit(u.w,h3,l3);
      ushort4 hv; hv.x=h0; hv.y=h1; hv.z=h2; hv.w=h3;
      ushort4 lv; lv.x=l0; lv.y=l1; lv.z=l2; lv.w=l3;
      *(ushort4*)(&sBh[c*SBS + sg*4]) = hv;
      *(ushort4*)(&sBl[c*SBS + sg*4]) = lv;
    }
    __syncthreads();
#pragma unroll
    for (int ct = 0; ct < 4; ++ct){
      const int ccol = ct*16 + l16;
      short8 bh[4], bl[4];
#pragma unroll
      for (int ks = 0; ks < 4; ++ks){
        bh[ks] = *(const short8*)(&sBh[ccol*SBS + ks*32 + quad*8]);
        bl[ks] = *(const short8*)(&sBl[ccol*SBS + ks*32 + quad*8]);
      }
      f32x4 acch = {0.f,0.f,0.f,0.f}, accx = {0.f,0.f,0.f,0.f};
#pragma unroll
      for (int ks = 0; ks < 4; ++ks){
        acch = __builtin_amdgcn_mfma_f32_16x16x32_bf16(ah[ks], bh[ks], acch, 0, 0, 0);
        accx = __builtin_amdgcn_mfma_f32_16x16x32_bf16(ah[ks], bl[ks], accx, 0, 0, 0);
        accx = __builtin_amdgcn_mfma_f32_16x16x32_bf16(al[ks], bh[ks], accx, 0, 0, 0);
      }
      const int col = n_base + rnd*64 + ct*16 + l16;
      const float y2v  = y2g[col];
      const float fbv  = fbg[col];
      const float y2p1 = 1.f + y2v;
#pragma unroll
      for (int r = 0; r < 4; ++r){
        float t   = acch[r] + accx[r];        // xy, f32-accurate
        float two = t + t;
        float a   = y2p1 - two;               // 1 - 2xy + y2
        float den = fmaf(x2v[r], y2v, 1.f - two);
        float dc  = fmaxf(den, 1e-15f);
        float num2 = fmaf(a*x2v[r], a, fmaf(ntb[r]*t, a, b2[r]*y2v));
        float sq  = sqrtf(fmaxf(num2, 0.f));
        float s   = fminf(sq, 0.99999f*dc);   // norm clip at 1-1e-5
        float d   = __logf(__fdividef(dc + s, dc - s));  // 2*artanh(s/dc)
        float outv = fmaf(d*d, nit2, fbv);
        outp[(size_t)(m0 + quad*4 + r)*32000 + col] = outv;
      }
    }
  }
}

extern "C" void kernel_launch(void* const* d_in, const int* in_sizes, int n_in,
                              void* d_out, int out_size, void* d_ws, size_t ws_size,
                              hipStream_t stream) {
  const float* vt   = (const float*)d_in[0];  // v_tangent [16,128,128]
  const float* code = (const float*)d_in[1];  // code_points [32000,128]
  const float* Wm   = (const float*)d_in[2];  // W [128,128]
  const float* bias = (const float*)d_in[3];  // b [128]
  const float* fb   = (const float*)d_in[4];  // freq_bias [32000]
  const float* temp = (const float*)d_in[5];  // temperature [1]
  float* outp = (float*)d_out;

  char* ws = (char*)d_ws;
  u16*   ahi = (u16*)ws;                           // 2048*128*2 = 512 KB
  u16*   alo = (u16*)(ws + 512*1024);              // 512 KB
  float* x2  = (float*)(ws + 1024*1024);           // 8 KB
  float* y2  = (float*)(ws + 1024*1024 + 8192);    // 128 KB

  prep_kernel<<<2048, 64, 0, stream>>>(vt, Wm, bias, ahi, alo, x2);
  y2_kernel<<<125, 256, 0, stream>>>(code, y2);
  dim3 grid(125, 32);
  decode_main<<<grid, 256, 0, stream>>>(code, ahi, alo, x2, y2, fb, temp, outp);
}

// Round 3
// 446.354 us; speedup vs baseline: 1.0050x; 1.0050x over previous
//
#include <hip/hip_runtime.h>
#include <hip/hip_bf16.h>

// All inputs/output are float32. GEMM precision: split-bf16 on BOTH operands,
// xy = AhBh + (AhBl + AlBh) -> f32-grade xy (artanh amplifies err ~1000x).
// R3 changes vs R2: (1) launch_bounds (256,3) to avoid VGPR spills (R2 forced
// 128 regs, est. live set ~150); (2) B pre-split once to ws (no per-round
// bfsplit VALU); (3) MFMA operands swapped -> float4 C stores + scalar
// per-row constants; (4) grid (rowgroup, colchunk) for B L2 sharing.

typedef __attribute__((ext_vector_type(8))) short short8;
typedef __attribute__((ext_vector_type(4))) float f32x4;
typedef unsigned short u16;

__device__ inline float bits2f(unsigned u){ union{unsigned u; float f;} x; x.u=u; return x.f; }
__device__ inline u16 f2bf(float f){
  union { float f; unsigned u; } x; x.f = f;
  unsigned r = x.u + 0x7fff + ((x.u >> 16) & 1);   // round-to-nearest-even
  return (u16)(r >> 16);
}
__device__ inline void bfsplit(float f, u16 &h, u16 &l){
  u16 hb = f2bf(f);
  float hf = bits2f(((unsigned)hb) << 16);
  h = hb;
  l = f2bf(f - hf);
}

__device__ inline float wred(float x){
#pragma unroll
  for (int off = 32; off; off >>= 1) x += __shfl_xor(x, off, 64);
  return x;
}
__device__ inline float wred32(float x){
#pragma unroll
  for (int off = 16; off; off >>= 1) x += __shfl_xor(x, off, 64);
  return x;
}

__device__ inline float dotW(const float* __restrict__ w, const float* __restrict__ p){
  float m = 0.f;
#pragma unroll
  for (int i = 0; i < 32; ++i){
    float4 u = *(const float4*)(w + 4*i);
    const float* q = p + 4*i;
    m = fmaf(u.x, q[0], m); m = fmaf(u.y, q[1], m);
    m = fmaf(u.z, q[2], m); m = fmaf(u.w, q[3], m);
  }
  return m;
}

// ---------------- Kernel 1: per-row hyperbolic MLP chain (f32) ----------------
__global__ __launch_bounds__(64) void prep_kernel(
    const float* __restrict__ vt, const float* __restrict__ Wm,
    const float* __restrict__ bias,
    u16* __restrict__ ahi, u16* __restrict__ alo, float* __restrict__ x2o)
{
  const int row = blockIdx.x, lane = threadIdx.x;
  const int e0 = 2*lane;
  const float CLIP = 0.99999f;  // 1 - 1e-5

  float v0 = vt[row*128 + e0];
  float v1 = vt[row*128 + e0 + 1];
  float n1 = fmaxf(sqrtf(wred(v0*v0 + v1*v1)), 1e-15f);
  float s1 = tanhf(n1)/n1;
  float p0 = s1*v0, p1 = s1*v1;
  __shared__ float sP[128];
  sP[e0] = p0; sP[e0+1] = p1;
  __syncthreads();
  float xn = fmaxf(sqrtf(wred(p0*p0 + p1*p1)), 1e-15f);
  float mx0 = dotW(Wm + e0*128, sP);
  float mx1 = dotW(Wm + (e0+1)*128, sP);
  float Mxn = fmaxf(sqrtf(wred(mx0*mx0 + mx1*mx1)), 1e-15f);
  float smv = tanhf((Mxn/xn) * atanhf(fminf(xn, CLIP))) / Mxn;
  float m0 = smv*mx0, m1 = smv*mx1;
  float b0 = bias[e0], b1 = bias[e0+1];
  float nb = fmaxf(sqrtf(wred(b0*b0 + b1*b1)), 1e-15f);
  float sb = tanhf(nb)/nb;
  float eb0 = sb*b0, eb1 = sb*b1;
  float x2m = wred(m0*m0 + m1*m1);
  float y2e = wred(eb0*eb0 + eb1*eb1);
  float xy  = wred(m0*eb0 + m1*eb1);
  float ca = 1.f + 2.f*xy + y2e;
  float cb = 1.f - x2m;
  float den = fmaxf(1.f + 2.f*xy + x2m*y2e, 1e-15f);
  float q0 = (ca*m0 + cb*eb0)/den, q1 = (ca*m1 + cb*eb1)/den;
  float n2 = fmaxf(sqrtf(wred(q0*q0 + q1*q1)), 1e-15f);
  float u = atanhf(fminf(n2, CLIP));
  float sv = u/n2;
  float w0v = sv*q0, w1v = sv*q1;
  float n3 = fmaxf(sqrtf(wred(w0v*w0v + w1v*w1v)), 1e-15f);
  float s3 = tanhf(n3)/n3;
  float P0 = s3*w0v, P1 = s3*w1v;
  float x2v = wred(P0*P0 + P1*P1);
  u16 h0, l0, h1, l1;
  bfsplit(P0, h0, l0); bfsplit(P1, h1, l1);
  ahi[row*128 + e0] = h0; ahi[row*128 + e0 + 1] = h1;
  alo[row*128 + e0] = l0; alo[row*128 + e0 + 1] = l1;
  if (lane == 0) x2o[row] = x2v;
}

// ------- Kernel 2: split code -> Bh/Bl (bf16) + y2 (one pass over code) -------
// 256 thr = 8 rows x 32 chunks; thread (r, c) handles float4 chunk c of row r.
__global__ __launch_bounds__(256) void split_y2_kernel(
    const float* __restrict__ code, u16* __restrict__ Bh,
    u16* __restrict__ Bl, float* __restrict__ y2o)
{
  const int c = threadIdx.x & 31, r = threadIdx.x >> 5;
  const int row = blockIdx.x*8 + r;
  float4 u = *(const float4*)(code + (size_t)row*128 + c*4);
  u16 h0,h1,h2,h3,l0,l1,l2,l3;
  bfsplit(u.x,h0,l0); bfsplit(u.y,h1,l1);
  bfsplit(u.z,h2,l2); bfsplit(u.w,h3,l3);
  ushort4 hv; hv.x=h0; hv.y=h1; hv.z=h2; hv.w=h3;
  ushort4 lv; lv.x=l0; lv.y=l1; lv.z=l2; lv.w=l3;
  *(ushort4*)(Bh + (size_t)row*128 + c*4) = hv;
  *(ushort4*)(Bl + (size_t)row*128 + c*4) = lv;
  float s = fmaf(u.x,u.x, fmaf(u.y,u.y, fmaf(u.z,u.z, u.w*u.w)));
  s = wred32(s);   // offsets 16..1 stay within each 32-lane half-wave
  if (c == 0) y2o[row] = s;
}

// ------- Kernel 3: split-bf16 GEMM + fused hyperbolic-dist epilogue -------
// Block: 256 thr = 4 waves; 64 rows (16/wave, A persistent in regs), 256 cols.
// Operand-swapped MFMA: D rows = act-row (lane&15), D cols = code col
// (quad*4+r, consecutive) -> float4 stores.
#define SBS 136   // 128 + 8 u16 pad; stride 272B: conflict-free in 8-lane phases

__global__ __launch_bounds__(256, 3) void decode_main(
    const u16* __restrict__ Bh_g, const u16* __restrict__ Bl_g,
    const u16* __restrict__ ahi_g, const u16* __restrict__ alo_g,
    const float* __restrict__ x2g, const float* __restrict__ y2g,
    const float* __restrict__ fbg, const float* __restrict__ tempg,
    float* __restrict__ outp)
{
  __shared__ u16 sBh[64*SBS];
  __shared__ u16 sBl[64*SBS];
  const int tid  = threadIdx.x;
  const int wave = tid >> 6, lane = tid & 63;
  const int quad = lane >> 4, l16 = lane & 15;
  const int m0 = blockIdx.x*64 + wave*16;   // row-group fastest -> B L2 sharing
  const int arow = m0 + l16;

  // Persistent A fragments (act): Y-operand layout [n=lane&15][k=quad*8+j]
  short8 ah[4], al[4];
#pragma unroll
  for (int ks = 0; ks < 4; ++ks){
    ah[ks] = *(const short8*)(ahi_g + arow*128 + ks*32 + quad*8);
    al[ks] = *(const short8*)(alo_g + arow*128 + ks*32 + quad*8);
  }
  // Per-row (per-lane) scalar precomputes
  const float xv  = x2g[arow];
  const float bb  = 1.f - xv;
  const float ntb = -2.f*bb;
  const float b2  = bb*bb;
  const float tmp  = tempg[0];
  const float nit2 = -1.f/(tmp*tmp);   // out = fb - d^2/t^2
  const int n_base = blockIdx.y*256;

  for (int rnd = 0; rnd < 4; ++rnd){
    const int n0r = n_base + rnd*64;
    __syncthreads();
    // stage 64 cols x K=128 of pre-split B into LDS (16B chunks)
#pragma unroll
    for (int i = 0; i < 4; ++i){
      int id = tid + i*256;            // 0..1023
      int c = id >> 4, sg = id & 15;   // col, 8xu16-chunk within col
      size_t goff = (size_t)(n0r + c)*128 + sg*8;
      *(uint4*)(&sBh[c*SBS + sg*8]) = *(const uint4*)(Bh_g + goff);
      *(uint4*)(&sBl[c*SBS + sg*8]) = *(const uint4*)(Bl_g + goff);
    }
    __syncthreads();
#pragma unroll
    for (int ct = 0; ct < 4; ++ct){
      const int ccol = ct*16 + l16;    // X-operand: code col = lane&15
      short8 bh[4], bl[4];
#pragma unroll
      for (int ks = 0; ks < 4; ++ks){
        bh[ks] = *(const short8*)(&sBh[ccol*SBS + ks*32 + quad*8]);
        bl[ks] = *(const short8*)(&sBl[ccol*SBS + ks*32 + quad*8]);
      }
      f32x4 acch = {0.f,0.f,0.f,0.f}, accx = {0.f,0.f,0.f,0.f};
#pragma unroll
      for (int ks = 0; ks < 4; ++ks){
        acch = __builtin_amdgcn_mfma_f32_16x16x32_bf16(bh[ks], ah[ks], acch, 0, 0, 0);
        accx = __builtin_amdgcn_mfma_f32_16x16x32_bf16(bl[ks], ah[ks], accx, 0, 0, 0);
        accx = __builtin_amdgcn_mfma_f32_16x16x32_bf16(bh[ks], al[ks], accx, 0, 0, 0);
      }
      // D[i=code col in tile][j=act row]: col = quad*4+r (consecutive), row = l16
      const int cbase = n0r + ct*16 + quad*4;
      const float4 y2v4 = *(const float4*)(y2g + cbase);
      const float4 fbv4 = *(const float4*)(fbg + cbase);
      float4 o;
#pragma unroll
      for (int r = 0; r < 4; ++r){
        float y2v = ((const float*)&y2v4)[r];
        float t   = acch[r] + accx[r];        // xy, f32-accurate
        float two = t + t;
        float a   = (1.f + y2v) - two;        // 1 - 2xy + y2
        float den = fmaf(xv, y2v, 1.f - two);
        float dc  = fmaxf(den, 1e-15f);
        float num2 = fmaf(a*xv, a, fmaf(ntb*t, a, b2*y2v));
        float sq  = sqrtf(fmaxf(num2, 0.f));
        float s   = fminf(sq, 0.99999f*dc);   // norm clip at 1-1e-5
        float d   = __logf(__fdividef(dc + s, dc - s));  // 2*artanh(s/dc)
        ((float*)&o)[r] = fmaf(d*d, nit2, ((const float*)&fbv4)[r]);
      }
      *(float4*)(outp + (size_t)arow*32000 + cbase) = o;
    }
  }
}

extern "C" void kernel_launch(void* const* d_in, const int* in_sizes, int n_in,
                              void* d_out, int out_size, void* d_ws, size_t ws_size,
                              hipStream_t stream) {
  const float* vt   = (const float*)d_in[0];  // v_tangent [16,128,128]
  const float* code = (const float*)d_in[1];  // code_points [32000,128]
  const float* Wm   = (const float*)d_in[2];  // W [128,128]
  const float* bias = (const float*)d_in[3];  // b [128]
  const float* fb   = (const float*)d_in[4];  // freq_bias [32000]
  const float* temp = (const float*)d_in[5];  // temperature [1]
  float* outp = (float*)d_out;

  char* ws = (char*)d_ws;
  u16*   ahi = (u16*)ws;                            // 512 KB
  u16*   alo = (u16*)(ws + 512*1024);               // 512 KB
  float* x2  = (float*)(ws + 1024*1024);            // 8 KB
  float* y2  = (float*)(ws + 1024*1024 + 8192);     // 128 KB
  u16*   Bh  = (u16*)(ws + 1280*1024);              // 8.192 MB
  u16*   Bl  = (u16*)(ws + 1280*1024 + 8192*1024);  // 8.192 MB

  prep_kernel<<<2048, 64, 0, stream>>>(vt, Wm, bias, ahi, alo, x2);
  split_y2_kernel<<<4000, 256, 0, stream>>>(code, Bh, Bl, y2);
  dim3 grid(32, 125);
  decode_main<<<grid, 256, 0, stream>>>(Bh, Bl, ahi, alo, x2, y2, fb, temp, outp);
}